// Round 5
// baseline (1494.778 us; speedup 1.0000x reference)
//
#include <hip/hip_runtime.h>
#include <math.h>

// N=100000 nodes, E=1600000 edges, F_IN=10 (+2 idx cols), H=128, G=1000 graphs, GAP=3
#define H 128
#define GAPLEN 3
#define DIN 18

static inline int ceil_div(int a, int b){ return (a + b - 1) / b; }

// ---------------- feats (PRE-SCALED by dis[i]) -> SLICED [3][N][8], cols 18..23 = 0 ----------------
__global__ void build_feats_k(const float* __restrict__ x, const float* __restrict__ se,
                              const float* __restrict__ ne, const float* __restrict__ dis,
                              float* __restrict__ fs, int n){
  int i = blockIdx.x * 256 + threadIdx.x;
  if (i >= n) return;
  const float* xr = x + (size_t)i * 12;
  float di = dis[i];
  float v[24];
#pragma unroll
  for (int c = 0; c < 10; ++c) v[c] = di * xr[c];
  int st = (int)xr[10];
  int nv = (int)xr[11];
#pragma unroll
  for (int c = 0; c < 4; ++c){
    v[10 + c] = di * se[st * 4 + c];
    v[14 + c] = di * ne[nv * 4 + c];
  }
#pragma unroll
  for (int c = 18; c < 24; ++c) v[c] = 0.f;
#pragma unroll
  for (int s = 0; s < 3; ++s){
    float* p = fs + ((size_t)s * n + i) * 8;
    *(float4*)(p)     = float4{v[s*8+0], v[s*8+1], v[s*8+2], v[s*8+3]};
    *(float4*)(p + 4) = float4{v[s*8+4], v[s*8+5], v[s*8+6], v[s*8+7]};
  }
}

// =================== bucketed CSR build (kept) ===================
#define CHUNK 4096

__global__ __launch_bounds__(256) void bhistA_k(const int* __restrict__ ei, int* __restrict__ bh,
                                                int E, int NB){
  __shared__ int lh[1024];
  int t = threadIdx.x;
  for (int j = t; j < 1024; j += 256) lh[j] = 0;
  __syncthreads();
  int base = blockIdx.x * CHUNK;
#pragma unroll
  for (int i = 0; i < 16; ++i){
    int e = base + i * 256 + t;
    if (e < E) atomicAdd(&lh[ei[E + e] >> 7], 1);
  }
  __syncthreads();
  for (int j = t; j < NB; j += 256){
    int v = lh[j];
    if (v) atomicAdd(&bh[j], v);
  }
}

__global__ void bscan_k(const int* __restrict__ bh, int* __restrict__ bbase, int NB){
  __shared__ int sd[1024];
  int t = threadIdx.x;
  int v = (t < NB) ? bh[t] : 0;
  sd[t] = v;
  __syncthreads();
  for (int off = 1; off < 1024; off <<= 1){
    int add = (t >= off) ? sd[t - off] : 0;
    __syncthreads();
    sd[t] += add;
    __syncthreads();
  }
  if (t < NB) bbase[t] = sd[t] - v;
}

__global__ __launch_bounds__(256) void bpartC_k(const int* __restrict__ ei,
                                                const int* __restrict__ bbase,
                                                int* __restrict__ bcur,
                                                int* __restrict__ ebuf, int E, int NB){
  __shared__ int lh[1024];
  __shared__ int lchunk[1024];
  __shared__ int lcur[1024];
  int t = threadIdx.x;
  for (int j = t; j < 1024; j += 256) lh[j] = 0;
  __syncthreads();
  int base = blockIdx.x * CHUNK;
  int pk[16], bk[16];
#pragma unroll
  for (int i = 0; i < 16; ++i){
    int e = base + i * 256 + t;
    if (e < E){
      int s = ei[e];
      int d = ei[E + e];
      bk[i] = d >> 7;
      pk[i] = ((d & 127) << 17) | s;
      atomicAdd(&lh[bk[i]], 1);
    } else bk[i] = -1;
  }
  __syncthreads();
  for (int j = t; j < NB; j += 256){
    int c = lh[j];
    if (c) lchunk[j] = bbase[j] + atomicAdd(&bcur[j], c);
    lcur[j] = 0;
  }
  __syncthreads();
#pragma unroll
  for (int i = 0; i < 16; ++i){
    if (bk[i] >= 0){
      int off = atomicAdd(&lcur[bk[i]], 1);
      ebuf[lchunk[bk[i]] + off] = pk[i];
    }
  }
}

__global__ __launch_bounds__(256) void bbuildD_k(const int* __restrict__ ebuf,
                                                 const int* __restrict__ bh,
                                                 const int* __restrict__ bbase,
                                                 int* __restrict__ rp, int* __restrict__ cnt,
                                                 float* __restrict__ dis, int* __restrict__ csr,
                                                 int n){
  __shared__ int hist[128], sc[128], gb[128], curr[128];
  int b = blockIdx.x;
  int t = threadIdx.x;
  int sb = bbase[b];
  int mb = bh[b];
  if (t < 128) hist[t] = 0;
  __syncthreads();
  for (int i = t; i < mb; i += 256)
    atomicAdd(&hist[ebuf[sb + i] >> 17], 1);
  __syncthreads();
  if (t < 128) sc[t] = hist[t];
  __syncthreads();
  for (int off = 1; off < 128; off <<= 1){
    int add = (t < 128 && t >= off) ? sc[t - off] : 0;
    __syncthreads();
    if (t < 128) sc[t] += add;
    __syncthreads();
  }
  if (t < 128){
    int node = b * 128 + t;
    int rpv = sb + sc[t] - hist[t];
    gb[t] = rpv;
    curr[t] = 0;
    if (node < n){
      rp[node] = rpv;
      cnt[node] = hist[t];
      dis[node] = rsqrtf((float)hist[t] + 1.0f);
    }
  }
  __syncthreads();
  for (int i = t; i < mb; i += 256){
    int p = ebuf[sb + i];
    int dl = p >> 17;
    int src = p & 0x1FFFF;
    int off = atomicAdd(&curr[dl], 1);
    csr[gb[dl] + off] = src;
  }
}

// =================== degree-sorted node permutation ===================
// counting sort on degree (256 bins); packs (rp, cnt, node, dis) per perm slot.
__global__ void dhist_k(const int* __restrict__ cnt, int* __restrict__ dh, int n){
  int i = blockIdx.x * 256 + threadIdx.x;
  if (i < n){
    int d = cnt[i]; if (d > 255) d = 255;
    atomicAdd(&dh[d], 1);
  }
}

__global__ void dscan_k(const int* __restrict__ dh, int* __restrict__ dbase){
  __shared__ int sd[256];
  int t = threadIdx.x;
  int v = dh[t];
  sd[t] = v;
  __syncthreads();
  for (int off = 1; off < 256; off <<= 1){
    int add = (t >= off) ? sd[t - off] : 0;
    __syncthreads();
    sd[t] += add;
    __syncthreads();
  }
  dbase[t] = sd[t] - v;
}

__global__ void dperm_k(const int* __restrict__ cnt, const int* __restrict__ rp,
                        const float* __restrict__ dis, const int* __restrict__ dbase,
                        int* __restrict__ dcur, int4* __restrict__ prc, int n){
  int i = blockIdx.x * 256 + threadIdx.x;
  if (i >= n) return;
  int d = cnt[i]; int db = d > 255 ? 255 : d;
  int pos = dbase[db] + atomicAdd(&dcur[db], 1);
  prc[pos] = int4{rp[i], d, i, __float_as_int(dis[i])};
}

// ---------------- sliced aggregation, degree-uniform waves ----------------
// MODE 0: H=128, 8 slices per launch (slice_base 0 or 8) -> one slice per XCD.
// MODE 1: feats [3][N][8]; 4 slots, slot 3 no-op.
// hs pre-scaled by dis[src]; out = dis[node]*(sum + self), unscaled.
template<int MODE>
__global__ __launch_bounds__(256) void aggp_k(const float* __restrict__ hs,
                                              const int4* __restrict__ prc,
                                              const int* __restrict__ csr,
                                              float* __restrict__ outs, int n, int slice_base){
  int bid = blockIdx.x;
  int slice, tile;
  if (MODE == 0){ slice = slice_base + (bid & 7); tile = bid >> 3; }
  else { slice = bid & 3; if (slice == 3) return; tile = bid >> 2; }
  int t = threadIdx.x;
  int i = tile * 128 + (t >> 1);
  if (i >= n) return;
  int4 v = prc[i];
  int start = v.x, m = v.y, node = v.z;
  float di = __int_as_float(v.w);
  int half = t & 1;
  const char* bp = (const char*)(hs + (size_t)slice * n * 8) + half * 16;
  float4 a0 = {0.f,0.f,0.f,0.f}, a1 = {0.f,0.f,0.f,0.f};
  int e = 0;
  for (; e + 8 <= m; e += 8){
    int s0 = csr[start+e],   s1 = csr[start+e+1], s2 = csr[start+e+2], s3 = csr[start+e+3];
    int s4 = csr[start+e+4], s5 = csr[start+e+5], s6 = csr[start+e+6], s7 = csr[start+e+7];
    float4 v0 = *(const float4*)(bp + ((size_t)s0 << 5));
    float4 v1 = *(const float4*)(bp + ((size_t)s1 << 5));
    float4 v2 = *(const float4*)(bp + ((size_t)s2 << 5));
    float4 v3 = *(const float4*)(bp + ((size_t)s3 << 5));
    float4 v4 = *(const float4*)(bp + ((size_t)s4 << 5));
    float4 v5 = *(const float4*)(bp + ((size_t)s5 << 5));
    float4 v6 = *(const float4*)(bp + ((size_t)s6 << 5));
    float4 v7 = *(const float4*)(bp + ((size_t)s7 << 5));
    a0.x += v0.x + v1.x + v2.x + v3.x;  a1.x += v4.x + v5.x + v6.x + v7.x;
    a0.y += v0.y + v1.y + v2.y + v3.y;  a1.y += v4.y + v5.y + v6.y + v7.y;
    a0.z += v0.z + v1.z + v2.z + v3.z;  a1.z += v4.z + v5.z + v6.z + v7.z;
    a0.w += v0.w + v1.w + v2.w + v3.w;  a1.w += v4.w + v5.w + v6.w + v7.w;
  }
  for (; e < m; ++e){
    int s = csr[start + e];
    float4 vv = *(const float4*)(bp + ((size_t)s << 5));
    a0.x += vv.x; a0.y += vv.y; a0.z += vv.z; a0.w += vv.w;
  }
  float4 self = *(const float4*)(bp + ((size_t)node << 5));
  float4 o;
  o.x = di * (a0.x + a1.x + self.x);
  o.y = di * (a0.y + a1.y + self.y);
  o.z = di * (a0.z + a1.z + self.z);
  o.w = di * (a0.w + a1.w + self.w);
  *(float4*)((char*)(outs + (size_t)slice * n * 8) + half * 16 + ((size_t)node << 5)) = o;
}

// ---------------- GEMM: [n,18](sliced A) @ [18,128] + bias, relu, x dis -> SLICED out ----------------
__global__ void gemm18_k(const float* __restrict__ A, const float* __restrict__ W,
                         const float* __restrict__ b, const float* __restrict__ dis,
                         float* __restrict__ C, int n){
  __shared__ float sw[DIN * H];
  __shared__ float sb[H];
  __shared__ float sa[8][DIN];
  int t = threadIdx.x;
  for (int i = t; i < DIN * H; i += 256) sw[i] = W[i];
  if (t < H) sb[t] = b[t];
  int row0 = blockIdx.x * 8;
  for (int i = t; i < 8 * DIN; i += 256){
    int r = i / DIN, c = i % DIN;
    int rr = row0 + r;
    sa[r][c] = (rr < n) ? A[(((size_t)(c >> 3) * n + rr) << 3) + (c & 7)] : 0.f;
  }
  __syncthreads();
  int r = t >> 5, lane = t & 31;
  int row = row0 + r;
  if (row >= n) return;
  int c0 = lane * 4;
  float ox = sb[c0], oy = sb[c0 + 1], oz = sb[c0 + 2], ow = sb[c0 + 3];
#pragma unroll
  for (int k = 0; k < DIN; ++k){
    float a = sa[r][k];
    const float4 w = *(const float4*)&sw[k * H + c0];
    ox += a * w.x; oy += a * w.y; oz += a * w.z; ow += a * w.w;
  }
  float di = dis[row];
  float4 o;
  o.x = di * fmaxf(ox, 0.f); o.y = di * fmaxf(oy, 0.f);
  o.z = di * fmaxf(oz, 0.f); o.w = di * fmaxf(ow, 0.f);
  *(float4*)&C[(((size_t)(c0 >> 3) * n + row) << 3) + (c0 & 7)] = o;
}

// ---------------- GEMM: [n,128](SLICED A) @ [128,128] + bias, relu ----------------
template<int OUTMODE>
__global__ __launch_bounds__(128) void gemm128_k(const float* __restrict__ A,
                                                 const float* __restrict__ B,
                                                 const float* __restrict__ bias,
                                                 const float* __restrict__ dis,
                                                 float* __restrict__ C, int n){
  __shared__ float sa[32][64];
  int t = threadIdx.x;
  int row0 = blockIdx.x * 64;
  int tc = t & 15;
  int tr = t >> 4;
  float acc[8][8];
#pragma unroll
  for (int i = 0; i < 8; ++i)
#pragma unroll
    for (int j = 0; j < 8; ++j) acc[i][j] = 0.f;

  int lr = t >> 1;
  int lc = (t & 1) * 16;
  for (int k0 = 0; k0 < H; k0 += 32){
    int row = row0 + lr;
    bool rowok = row < n;
    int sl = (k0 + lc) >> 3;
    float4 v0, v1, v2, v3;
    if (rowok){
      const float* Ap0 = A + (((size_t)sl * n + row) << 3);
      const float* Ap1 = A + (((size_t)(sl + 1) * n + row) << 3);
      v0 = *(const float4*)(Ap0);
      v1 = *(const float4*)(Ap0 + 4);
      v2 = *(const float4*)(Ap1);
      v3 = *(const float4*)(Ap1 + 4);
    } else {
      v0 = v1 = v2 = v3 = float4{0.f, 0.f, 0.f, 0.f};
    }
    __syncthreads();
    float vv[16] = {v0.x, v0.y, v0.z, v0.w, v1.x, v1.y, v1.z, v1.w,
                    v2.x, v2.y, v2.z, v2.w, v3.x, v3.y, v3.z, v3.w};
#pragma unroll
    for (int i = 0; i < 16; ++i) sa[lc + i][lr] = vv[i];
    __syncthreads();

    const float* Bp = B + (size_t)k0 * H + tc * 8;
#pragma unroll
    for (int k = 0; k < 32; ++k){
      float4 b0 = *(const float4*)(Bp + (size_t)k * H);
      float4 b1 = *(const float4*)(Bp + (size_t)k * H + 4);
      float4 a0 = *(const float4*)&sa[k][tr * 8];
      float4 a1 = *(const float4*)&sa[k][tr * 8 + 4];
      float aa[8] = {a0.x, a0.y, a0.z, a0.w, a1.x, a1.y, a1.z, a1.w};
      float bb[8] = {b0.x, b0.y, b0.z, b0.w, b1.x, b1.y, b1.z, b1.w};
#pragma unroll
      for (int i = 0; i < 8; ++i)
#pragma unroll
        for (int j = 0; j < 8; ++j) acc[i][j] += aa[i] * bb[j];
    }
  }
  float bb[8];
#pragma unroll
  for (int j = 0; j < 8; ++j) bb[j] = bias[tc * 8 + j];
#pragma unroll
  for (int i = 0; i < 8; ++i){
    int row = row0 + tr * 8 + i;
    if (row < n){
      float4 o0, o1;
      o0.x = fmaxf(acc[i][0] + bb[0], 0.f);
      o0.y = fmaxf(acc[i][1] + bb[1], 0.f);
      o0.z = fmaxf(acc[i][2] + bb[2], 0.f);
      o0.w = fmaxf(acc[i][3] + bb[3], 0.f);
      o1.x = fmaxf(acc[i][4] + bb[4], 0.f);
      o1.y = fmaxf(acc[i][5] + bb[5], 0.f);
      o1.z = fmaxf(acc[i][6] + bb[6], 0.f);
      o1.w = fmaxf(acc[i][7] + bb[7], 0.f);
      if (OUTMODE == 0){
        float di = dis[row];
        o0.x *= di; o0.y *= di; o0.z *= di; o0.w *= di;
        o1.x *= di; o1.y *= di; o1.z *= di; o1.w *= di;
        float* Cp = C + (((size_t)tc * n + row) << 3);
        *(float4*)(Cp) = o0;
        *(float4*)(Cp + 4) = o1;
      } else {
        float* Cp = C + (size_t)row * H + tc * 8;
        *(float4*)(Cp) = o0;
        *(float4*)(Cp + 4) = o1;
      }
    }
  }
}

// ---------------- graph offsets ----------------
__global__ void ghist_k(const int* __restrict__ batch, int* __restrict__ gc, int n){
  int i = blockIdx.x * 256 + threadIdx.x;
  if (i < n) atomicAdd(&gc[batch[i]], 1);
}

__global__ void gscan_k(const int* __restrict__ gc, int* __restrict__ go, int G){
  __shared__ int sd[1024];
  int t = threadIdx.x;
  int v = (t < G) ? gc[t] : 0;
  sd[t] = v;
  __syncthreads();
  for (int off = 1; off < 1024; off <<= 1){
    int add = (t >= off) ? sd[t - off] : 0;
    __syncthreads();
    sd[t] += add;
    __syncthreads();
  }
  if (t < G) go[t] = sd[t] - v;
}

// ---------------- fused decoder: 3 steps x (GRU f + GRU b + post) ----------------
// 4 graphs per block, 1 wave per graph; all state in LDS, block-local.
__device__ __forceinline__ float sigf(float x){ return 1.f / (1.f + expf(-x)); }

__global__ __launch_bounds__(256) void decoder_k(
    const float* __restrict__ h3, const int* __restrict__ go, const int* __restrict__ gap,
    const float* __restrict__ Wih_f, const float* __restrict__ Whh_f,
    const float* __restrict__ bih_f, const float* __restrict__ bhh_f,
    const float* __restrict__ Wih_b, const float* __restrict__ Whh_b,
    const float* __restrict__ bih_b, const float* __restrict__ bhh_b,
    const float* __restrict__ Wred, const float* __restrict__ bred,
    const float* __restrict__ Wh1, const float* __restrict__ bh1,
    const float* __restrict__ Wh2, const float* __restrict__ bh2,
    float* __restrict__ out, int G){
  __shared__ float sx[4][H], shf[4][H], shb[4][H];
  int t = threadIdx.x;
  int g = t >> 6, l = t & 63;
  int gg = blockIdx.x * 4 + g;
  bool ok = gg < G;
  int idx = ok ? (go[gg] + gap[0]) : 0;
  float v0 = ok ? h3[(size_t)idx * H + l] : 0.f;
  float v1 = ok ? h3[(size_t)idx * H + 64 + l] : 0.f;
  sx[g][l] = v0; sx[g][64 + l] = v1;
  shf[g][l] = v0; shf[g][64 + l] = v1;
  shb[g][l] = v0; shb[g][64 + l] = v1;

  float bif[6], bhfv[6], bib[6], bhbv[6];
#pragma unroll
  for (int q = 0; q < 6; ++q){
    bif[q]  = bih_f[l + 64*q];  bhfv[q] = bhh_f[l + 64*q];
    bib[q]  = bih_b[l + 64*q];  bhbv[q] = bhh_b[l + 64*q];
  }
  float br0 = bred[l], br1 = bred[64 + l];
  float b10 = bh1[l],  b11 = bh1[64 + l];
  float w20 = Wh2[l*2], w21 = Wh2[l*2 + 1];
  float w22 = Wh2[(64+l)*2], w23 = Wh2[(64+l)*2 + 1];
  float b2o0 = bh2[0], b2o1 = bh2[1];
  __syncthreads();

  for (int step = 0; step < GAPLEN; ++step){
    // --- both GRU cells: gi = x@Wih, gh = h@Whh (j = l + 64q, q: 0,1=r 2,3=z 4,5=n) ---
    float af[6] = {0,0,0,0,0,0}, ahf[6] = {0,0,0,0,0,0};
    float ab[6] = {0,0,0,0,0,0}, ahb[6] = {0,0,0,0,0,0};
    for (int k = 0; k < H; ++k){
      float xk = sx[g][k], hfk = shf[g][k], hbk = shb[g][k];
      const float* wif = Wih_f + (size_t)k * 384;
      const float* whf = Whh_f + (size_t)k * 384;
      const float* wib = Wih_b + (size_t)k * 384;
      const float* whb = Whh_b + (size_t)k * 384;
#pragma unroll
      for (int q = 0; q < 6; ++q){
        af[q]  += xk  * wif[l + 64*q];
        ahf[q] += hfk * whf[l + 64*q];
        ab[q]  += xk  * wib[l + 64*q];
        ahb[q] += hbk * whb[l + 64*q];
      }
    }
    float hf0 = shf[g][l], hf1 = shf[g][64 + l];
    float hb0 = shb[g][l], hb1 = shb[g][64 + l];
    float rf0 = sigf(af[0] + bif[0] + ahf[0] + bhfv[0]);
    float rf1 = sigf(af[1] + bif[1] + ahf[1] + bhfv[1]);
    float zf0 = sigf(af[2] + bif[2] + ahf[2] + bhfv[2]);
    float zf1 = sigf(af[3] + bif[3] + ahf[3] + bhfv[3]);
    float nf0 = tanhf(af[4] + bif[4] + rf0 * (ahf[4] + bhfv[4]));
    float nf1 = tanhf(af[5] + bif[5] + rf1 * (ahf[5] + bhfv[5]));
    float nhf0 = (1.f - zf0) * nf0 + zf0 * hf0;
    float nhf1 = (1.f - zf1) * nf1 + zf1 * hf1;
    float rb0 = sigf(ab[0] + bib[0] + ahb[0] + bhbv[0]);
    float rb1 = sigf(ab[1] + bib[1] + ahb[1] + bhbv[1]);
    float zb0 = sigf(ab[2] + bib[2] + ahb[2] + bhbv[2]);
    float zb1 = sigf(ab[3] + bib[3] + ahb[3] + bhbv[3]);
    float nb0 = tanhf(ab[4] + bib[4] + rb0 * (ahb[4] + bhbv[4]));
    float nb1 = tanhf(ab[5] + bib[5] + rb1 * (ahb[5] + bhbv[5]));
    float nhb0 = (1.f - zb0) * nb0 + zb0 * hb0;
    float nhb1 = (1.f - zb1) * nb1 + zb1 * hb1;
    __syncthreads();   // drain k-loop LDS reads before overwrite
    shf[g][l] = nhf0; shf[g][64 + l] = nhf1;
    shb[g][l] = nhb0; shb[g][64 + l] = nhb1;
    __syncthreads();

    // --- post: out256 = [hf||hb]; a1 = out@Wh1 (j=l,l+64), a2 = out@Wred ---
    float a10 = 0.f, a11 = 0.f, a20 = 0.f, a21 = 0.f;
    for (int k = 0; k < 2 * H; ++k){
      float ok_ = (k < H) ? shf[g][k] : shb[g][k - H];
      const float* w1 = Wh1 + (size_t)k * H;
      const float* w2 = Wred + (size_t)k * H;
      a10 += ok_ * w1[l];      a11 += ok_ * w1[64 + l];
      a20 += ok_ * w2[l];      a21 += ok_ * w2[64 + l];
    }
    float t10 = fmaxf(a10 + b10, 0.f);
    float t11 = fmaxf(a11 + b11, 0.f);
    float p0 = t10 * w20 + t11 * w22;
    float p1 = t10 * w21 + t11 * w23;
#pragma unroll
    for (int o = 32; o > 0; o >>= 1){
      p0 += __shfl_down(p0, o, 64);
      p1 += __shfl_down(p1, o, 64);
    }
    if (ok && l == 0){
      out[((size_t)gg * GAPLEN + step) * 2 + 0] = p0 + b2o0;
      out[((size_t)gg * GAPLEN + step) * 2 + 1] = p1 + b2o1;
    }
    __syncthreads();   // drain post LDS reads before sx overwrite
    sx[g][l] = a20 + br0;
    sx[g][64 + l] = a21 + br1;
    __syncthreads();
  }
}

// =======================================================================
extern "C" void kernel_launch(void* const* d_in, const int* in_sizes, int n_in,
                              void* d_out, int out_size, void* d_ws, size_t ws_size,
                              hipStream_t stream) {
  const float* x     = (const float*)d_in[0];
  const int*   ei    = (const int*)d_in[1];
  const int*   batch = (const int*)d_in[2];
  const float* semb  = (const float*)d_in[3];
  const float* nemb  = (const float*)d_in[4];
  const float* W1 = (const float*)d_in[5];  const float* b1 = (const float*)d_in[6];
  const float* W2 = (const float*)d_in[7];  const float* b2 = (const float*)d_in[8];
  const float* W3 = (const float*)d_in[9];  const float* b3 = (const float*)d_in[10];
  const float* Wih_f = (const float*)d_in[11]; const float* Whh_f = (const float*)d_in[12];
  const float* bih_f = (const float*)d_in[13]; const float* bhh_f = (const float*)d_in[14];
  const float* Wih_b = (const float*)d_in[15]; const float* Whh_b = (const float*)d_in[16];
  const float* bih_b = (const float*)d_in[17]; const float* bhh_b = (const float*)d_in[18];
  const float* Wred = (const float*)d_in[19]; const float* bred = (const float*)d_in[20];
  const float* Wh1  = (const float*)d_in[21]; const float* bh1  = (const float*)d_in[22];
  const float* Wh2  = (const float*)d_in[23]; const float* bh2  = (const float*)d_in[24];
  const int* gap = (const int*)d_in[26];

  int N = in_sizes[0] / 12;
  int E = in_sizes[1] / 2;
  int G = out_size / (GAPLEN * 2);
  int NB = ceil_div(N, 128);
  float* out = (float*)d_out;

  char* ws = (char*)d_ws;
  size_t off = 0;
  auto alloc = [&](size_t bytes) -> void* {
    void* p = ws + off;
    off += (bytes + 511) & ~(size_t)511;
    return p;
  };
  float* feats  = (float*)alloc((size_t)N * 24 * 4);   // sliced [3][N][8]
  float* agg1   = (float*)alloc((size_t)N * 24 * 4);   // sliced [3][N][8]
  float* sl1    = (float*)alloc((size_t)N * H * 4);    // sliced A / final row-major h3
  float* sl2    = (float*)alloc((size_t)N * H * 4);    // sliced B
  int*   cnt    = (int*)alloc((size_t)N * 4);
  float* dis    = (float*)alloc((size_t)N * 4);
  int*   rp     = (int*)alloc((size_t)N * 4);
  int*   csr    = (int*)alloc((size_t)E * 4);
  int*   ebuf   = (int*)alloc((size_t)E * 4);
  int4*  prc    = (int4*)alloc((size_t)N * 16);
  int*   bh     = (int*)alloc((size_t)NB * 4);
  int*   bbase  = (int*)alloc((size_t)NB * 4);
  int*   bcur   = (int*)alloc((size_t)NB * 4);
  int*   dh     = (int*)alloc(256 * 4);
  int*   dbase  = (int*)alloc(256 * 4);
  int*   dcur   = (int*)alloc(256 * 4);
  int*   gc     = (int*)alloc((size_t)G * 4);
  int*   go     = (int*)alloc((size_t)G * 4);
  (void)ws_size; (void)n_in;

  hipMemsetAsync(bh, 0, (size_t)NB * 4, stream);
  hipMemsetAsync(bcur, 0, (size_t)NB * 4, stream);
  hipMemsetAsync(dh, 0, 256 * 4, stream);
  hipMemsetAsync(dcur, 0, 256 * 4, stream);
  hipMemsetAsync(gc, 0, (size_t)G * 4, stream);

  int nb256 = ceil_div(N, 256);
  int ebC   = ceil_div(E, CHUNK);

  // CSR build -> dis -> degree-sorted perm (prc) -> pre-scaled sliced feats
  bhistA_k<<<ebC, 256, 0, stream>>>(ei, bh, E, NB);
  bscan_k<<<1, 1024, 0, stream>>>(bh, bbase, NB);
  bpartC_k<<<ebC, 256, 0, stream>>>(ei, bbase, bcur, ebuf, E, NB);
  bbuildD_k<<<NB, 256, 0, stream>>>(ebuf, bh, bbase, rp, cnt, dis, csr, N);
  dhist_k<<<nb256, 256, 0, stream>>>(cnt, dh, N);
  dscan_k<<<1, 256, 0, stream>>>(dh, dbase);
  dperm_k<<<nb256, 256, 0, stream>>>(cnt, rp, dis, dbase, dcur, prc, N);
  build_feats_k<<<nb256, 256, 0, stream>>>(x, semb, nemb, dis, feats, N);

  int TB = ceil_div(N, 128);
  int gemmb = ceil_div(N, 64);

  // layer 1: sliced agg (3 slices of 4 slots) -> gemm18 (sliced+scaled out)
  aggp_k<1><<<4 * TB, 256, 0, stream>>>(feats, prc, csr, agg1, N, 0);
  gemm18_k<<<ceil_div(N, 8), 256, 0, stream>>>(agg1, W1, b1, dis, sl1, N);
  // layer 2: two phase-split launches (slices 0-7, then 8-15) -> gemm
  aggp_k<0><<<8 * TB, 256, 0, stream>>>(sl1, prc, csr, sl2, N, 0);
  aggp_k<0><<<8 * TB, 256, 0, stream>>>(sl1, prc, csr, sl2, N, 8);
  gemm128_k<0><<<gemmb, 128, 0, stream>>>(sl2, W2, b2, dis, sl1, N);
  // layer 3
  aggp_k<0><<<8 * TB, 256, 0, stream>>>(sl1, prc, csr, sl2, N, 0);
  aggp_k<0><<<8 * TB, 256, 0, stream>>>(sl1, prc, csr, sl2, N, 8);
  gemm128_k<1><<<gemmb, 128, 0, stream>>>(sl2, W3, b3, dis, sl1, N);  // sl1 = row-major h3

  // graph offsets + fused decoder
  ghist_k<<<nb256, 256, 0, stream>>>(batch, gc, N);
  gscan_k<<<1, 1024, 0, stream>>>(gc, go, G);
  decoder_k<<<ceil_div(G, 4), 256, 0, stream>>>(sl1, go, gap,
                                                Wih_f, Whh_f, bih_f, bhh_f,
                                                Wih_b, Whh_b, bih_b, bhh_b,
                                                Wred, bred, Wh1, bh1, Wh2, bh2,
                                                out, G);
}

// Round 6
// 936.462 us; speedup vs baseline: 1.5962x; 1.5962x over previous
//
#include <hip/hip_runtime.h>
#include <math.h>

// N=100000 nodes, E=1600000 edges, F_IN=10 (+2 idx cols), H=128, G=1000 graphs, GAP=3
#define H 128
#define GAPLEN 3
#define DIN 18

static inline int ceil_div(int a, int b){ return (a + b - 1) / b; }

// =================== bucketed CSR build ===================
#define CHUNK 4096

__global__ __launch_bounds__(256) void bhistA_k(const int* __restrict__ ei, int* __restrict__ bh,
                                                int E, int NB){
  __shared__ int lh[1024];
  int t = threadIdx.x;
  for (int j = t; j < 1024; j += 256) lh[j] = 0;
  __syncthreads();
  int base = blockIdx.x * CHUNK;
#pragma unroll
  for (int i = 0; i < 16; ++i){
    int e = base + i * 256 + t;
    if (e < E) atomicAdd(&lh[ei[E + e] >> 7], 1);
  }
  __syncthreads();
  for (int j = t; j < NB; j += 256){
    int v = lh[j];
    if (v) atomicAdd(&bh[j], v);
  }
}

__global__ void bscan_k(const int* __restrict__ bh, int* __restrict__ bbase, int NB){
  __shared__ int sd[1024];
  int t = threadIdx.x;
  int v = (t < NB) ? bh[t] : 0;
  sd[t] = v;
  __syncthreads();
  for (int off = 1; off < 1024; off <<= 1){
    int add = (t >= off) ? sd[t - off] : 0;
    __syncthreads();
    sd[t] += add;
    __syncthreads();
  }
  if (t < NB) bbase[t] = sd[t] - v;
}

__global__ __launch_bounds__(256) void bpartC_k(const int* __restrict__ ei,
                                                const int* __restrict__ bbase,
                                                int* __restrict__ bcur,
                                                int* __restrict__ ebuf, int E, int NB){
  __shared__ int lh[1024];
  __shared__ int lchunk[1024];
  __shared__ int lcur[1024];
  int t = threadIdx.x;
  for (int j = t; j < 1024; j += 256) lh[j] = 0;
  __syncthreads();
  int base = blockIdx.x * CHUNK;
  int pk[16], bk[16];
#pragma unroll
  for (int i = 0; i < 16; ++i){
    int e = base + i * 256 + t;
    if (e < E){
      int s = ei[e];
      int d = ei[E + e];
      bk[i] = d >> 7;
      pk[i] = ((d & 127) << 17) | s;
      atomicAdd(&lh[bk[i]], 1);
    } else bk[i] = -1;
  }
  __syncthreads();
  for (int j = t; j < NB; j += 256){
    int c = lh[j];
    if (c) lchunk[j] = bbase[j] + atomicAdd(&bcur[j], c);
    lcur[j] = 0;
  }
  __syncthreads();
#pragma unroll
  for (int i = 0; i < 16; ++i){
    if (bk[i] >= 0){
      int off = atomicAdd(&lcur[bk[i]], 1);
      ebuf[lchunk[bk[i]] + off] = pk[i];
    }
  }
}

__global__ __launch_bounds__(256) void bbuildD_k(const int* __restrict__ ebuf,
                                                 const int* __restrict__ bh,
                                                 const int* __restrict__ bbase,
                                                 int* __restrict__ rp, int* __restrict__ cnt,
                                                 float* __restrict__ dis, int* __restrict__ csr,
                                                 int n){
  __shared__ int hist[128], sc[128], gb[128], curr[128];
  int b = blockIdx.x;
  int t = threadIdx.x;
  int sb = bbase[b];
  int mb = bh[b];
  if (t < 128) hist[t] = 0;
  __syncthreads();
  for (int i = t; i < mb; i += 256)
    atomicAdd(&hist[ebuf[sb + i] >> 17], 1);
  __syncthreads();
  if (t < 128) sc[t] = hist[t];
  __syncthreads();
  for (int off = 1; off < 128; off <<= 1){
    int add = (t < 128 && t >= off) ? sc[t - off] : 0;
    __syncthreads();
    if (t < 128) sc[t] += add;
    __syncthreads();
  }
  if (t < 128){
    int node = b * 128 + t;
    int rpv = sb + sc[t] - hist[t];
    gb[t] = rpv;
    curr[t] = 0;
    if (node < n){
      rp[node] = rpv;
      cnt[node] = hist[t];
      dis[node] = rsqrtf((float)hist[t] + 1.0f);
    }
  }
  __syncthreads();
  for (int i = t; i < mb; i += 256){
    int p = ebuf[sb + i];
    int dl = p >> 17;
    int src = p & 0x1FFFF;
    int off = atomicAdd(&curr[dl], 1);
    csr[gb[dl] + off] = src;
  }
}

// =================== degree-sorted permutation (block-staged, low contention) ===================
__global__ void dhist_k(const int* __restrict__ cnt, int* __restrict__ dh, int n){
  __shared__ int lh[256];
  int t = threadIdx.x;
  lh[t] = 0;
  __syncthreads();
  int i = blockIdx.x * 256 + t;
  if (i < n){
    int d = cnt[i]; if (d > 255) d = 255;
    atomicAdd(&lh[d], 1);
  }
  __syncthreads();
  if (lh[t]) atomicAdd(&dh[t], lh[t]);
}

__global__ void dscan_k(const int* __restrict__ dh, int* __restrict__ dbase){
  __shared__ int sd[256];
  int t = threadIdx.x;
  int v = dh[t];
  sd[t] = v;
  __syncthreads();
  for (int off = 1; off < 256; off <<= 1){
    int add = (t >= off) ? sd[t - off] : 0;
    __syncthreads();
    sd[t] += add;
    __syncthreads();
  }
  dbase[t] = sd[t] - v;
}

// per-block chunk reservation: ONE global atomic per (block,bin)
__global__ void dperm_k(const int* __restrict__ cnt, const int* __restrict__ rp,
                        const float* __restrict__ dis, const int* __restrict__ dbase,
                        int* __restrict__ dcur, int4* __restrict__ prc,
                        float* __restrict__ disp, int* __restrict__ inv, int n){
  __shared__ int lh[256], lbase[256], lcur[256];
  int t = threadIdx.x;
  lh[t] = 0;
  __syncthreads();
  int i = blockIdx.x * 256 + t;
  bool ok = i < n;
  int d = 0, db = 0;
  if (ok){
    d = cnt[i]; db = d > 255 ? 255 : d;
    atomicAdd(&lh[db], 1);
  }
  __syncthreads();
  int c = lh[t];
  lcur[t] = 0;
  if (c) lbase[t] = dbase[t] + atomicAdd(&dcur[t], c);
  __syncthreads();
  if (ok){
    int off = atomicAdd(&lcur[db], 1);
    int pos = lbase[db] + off;
    float dv = dis[i];
    prc[pos] = int4{rp[i], d, i, __float_as_int(dv)};
    disp[pos] = dv;
    inv[i] = pos;
  }
}

// remap csr src values -> perm indices (in place)
__global__ void remap_k(int* __restrict__ csr, const int* __restrict__ inv, int E){
  int j = blockIdx.x * 256 + threadIdx.x;
  if (j < E) csr[j] = inv[csr[j]];
}

// ---------------- feats (pre-scaled by dis) -> SLICED [3][N][8] in PERM space ----------------
__global__ void build_feats_k(const float* __restrict__ x, const float* __restrict__ se,
                              const float* __restrict__ ne, const int4* __restrict__ prc,
                              float* __restrict__ fs, int n){
  int i = blockIdx.x * 256 + threadIdx.x;
  if (i >= n) return;
  int4 pv = prc[i];
  int node = pv.z;
  float di = __int_as_float(pv.w);
  const float* xr = x + (size_t)node * 12;
  float v[24];
#pragma unroll
  for (int c = 0; c < 10; ++c) v[c] = di * xr[c];
  int st = (int)xr[10];
  int nv = (int)xr[11];
#pragma unroll
  for (int c = 0; c < 4; ++c){
    v[10 + c] = di * se[st * 4 + c];
    v[14 + c] = di * ne[nv * 4 + c];
  }
#pragma unroll
  for (int c = 18; c < 24; ++c) v[c] = 0.f;
#pragma unroll
  for (int s = 0; s < 3; ++s){
    float* p = fs + ((size_t)s * n + i) * 8;
    *(float4*)(p)     = float4{v[s*8+0], v[s*8+1], v[s*8+2], v[s*8+3]};
    *(float4*)(p + 4) = float4{v[s*8+4], v[s*8+5], v[s*8+6], v[s*8+7]};
  }
}

// ---------------- sliced aggregation in PERM space ----------------
// MODE 0: H=128, 8 slices per launch (slice_base 0 or 8), one slice per XCD.
// MODE 1: feats [3][N][8]; 4 slots, slot 3 no-op.
// Everything (self row, out row, prc) indexed by perm slot i -> coalesced;
// csr values are perm indices; waves are degree-uniform.
template<int MODE>
__global__ __launch_bounds__(256) void aggp_k(const float* __restrict__ hs,
                                              const int4* __restrict__ prc,
                                              const int* __restrict__ csr,
                                              float* __restrict__ outs, int n, int slice_base){
  int bid = blockIdx.x;
  int slice, tile;
  if (MODE == 0){ slice = slice_base + (bid & 7); tile = bid >> 3; }
  else { slice = bid & 3; if (slice == 3) return; tile = bid >> 2; }
  int t = threadIdx.x;
  int i = tile * 128 + (t >> 1);
  if (i >= n) return;
  int4 v = prc[i];
  int start = v.x, m = v.y;
  float di = __int_as_float(v.w);
  int half = t & 1;
  const char* bp = (const char*)(hs + (size_t)slice * n * 8) + half * 16;
  float4 a0 = {0.f,0.f,0.f,0.f}, a1 = {0.f,0.f,0.f,0.f};
  int e = 0;
  for (; e + 8 <= m; e += 8){
    int s0 = csr[start+e],   s1 = csr[start+e+1], s2 = csr[start+e+2], s3 = csr[start+e+3];
    int s4 = csr[start+e+4], s5 = csr[start+e+5], s6 = csr[start+e+6], s7 = csr[start+e+7];
    float4 v0 = *(const float4*)(bp + ((size_t)s0 << 5));
    float4 v1 = *(const float4*)(bp + ((size_t)s1 << 5));
    float4 v2 = *(const float4*)(bp + ((size_t)s2 << 5));
    float4 v3 = *(const float4*)(bp + ((size_t)s3 << 5));
    float4 v4 = *(const float4*)(bp + ((size_t)s4 << 5));
    float4 v5 = *(const float4*)(bp + ((size_t)s5 << 5));
    float4 v6 = *(const float4*)(bp + ((size_t)s6 << 5));
    float4 v7 = *(const float4*)(bp + ((size_t)s7 << 5));
    a0.x += v0.x + v1.x + v2.x + v3.x;  a1.x += v4.x + v5.x + v6.x + v7.x;
    a0.y += v0.y + v1.y + v2.y + v3.y;  a1.y += v4.y + v5.y + v6.y + v7.y;
    a0.z += v0.z + v1.z + v2.z + v3.z;  a1.z += v4.z + v5.z + v6.z + v7.z;
    a0.w += v0.w + v1.w + v2.w + v3.w;  a1.w += v4.w + v5.w + v6.w + v7.w;
  }
  for (; e < m; ++e){
    int s = csr[start + e];
    float4 vv = *(const float4*)(bp + ((size_t)s << 5));
    a0.x += vv.x; a0.y += vv.y; a0.z += vv.z; a0.w += vv.w;
  }
  float4 self = *(const float4*)(bp + ((size_t)i << 5));
  float4 o;
  o.x = di * (a0.x + a1.x + self.x);
  o.y = di * (a0.y + a1.y + self.y);
  o.z = di * (a0.z + a1.z + self.z);
  o.w = di * (a0.w + a1.w + self.w);
  *(float4*)((char*)(outs + (size_t)slice * n * 8) + half * 16 + ((size_t)i << 5)) = o;
}

// ---------------- GEMM: [n,18](sliced, perm) @ [18,128] + bias, relu, x disp -> SLICED perm out ----------------
__global__ void gemm18_k(const float* __restrict__ A, const float* __restrict__ W,
                         const float* __restrict__ b, const float* __restrict__ disp,
                         float* __restrict__ C, int n){
  __shared__ float sw[DIN * H];
  __shared__ float sb[H];
  __shared__ float sa[8][DIN];
  int t = threadIdx.x;
  for (int i = t; i < DIN * H; i += 256) sw[i] = W[i];
  if (t < H) sb[t] = b[t];
  int row0 = blockIdx.x * 8;
  for (int i = t; i < 8 * DIN; i += 256){
    int r = i / DIN, c = i % DIN;
    int rr = row0 + r;
    sa[r][c] = (rr < n) ? A[(((size_t)(c >> 3) * n + rr) << 3) + (c & 7)] : 0.f;
  }
  __syncthreads();
  int r = t >> 5, lane = t & 31;
  int row = row0 + r;
  if (row >= n) return;
  int c0 = lane * 4;
  float ox = sb[c0], oy = sb[c0 + 1], oz = sb[c0 + 2], ow = sb[c0 + 3];
#pragma unroll
  for (int k = 0; k < DIN; ++k){
    float a = sa[r][k];
    const float4 w = *(const float4*)&sw[k * H + c0];
    ox += a * w.x; oy += a * w.y; oz += a * w.z; ow += a * w.w;
  }
  float di = disp[row];
  float4 o;
  o.x = di * fmaxf(ox, 0.f); o.y = di * fmaxf(oy, 0.f);
  o.z = di * fmaxf(oz, 0.f); o.w = di * fmaxf(ow, 0.f);
  *(float4*)&C[(((size_t)(c0 >> 3) * n + row) << 3) + (c0 & 7)] = o;
}

// ---------------- GEMM: [n,128](SLICED perm A) @ [128,128] + bias, relu ----------------
// OUTMODE 0: sliced perm out, scaled by disp.  OUTMODE 1: row-major perm out, unscaled.
template<int OUTMODE>
__global__ __launch_bounds__(128) void gemm128_k(const float* __restrict__ A,
                                                 const float* __restrict__ B,
                                                 const float* __restrict__ bias,
                                                 const float* __restrict__ disp,
                                                 float* __restrict__ C, int n){
  __shared__ float sa[32][64];
  int t = threadIdx.x;
  int row0 = blockIdx.x * 64;
  int tc = t & 15;
  int tr = t >> 4;
  float acc[8][8];
#pragma unroll
  for (int i = 0; i < 8; ++i)
#pragma unroll
    for (int j = 0; j < 8; ++j) acc[i][j] = 0.f;

  int lr = t >> 1;
  int lc = (t & 1) * 16;
  for (int k0 = 0; k0 < H; k0 += 32){
    int row = row0 + lr;
    bool rowok = row < n;
    int sl = (k0 + lc) >> 3;
    float4 v0, v1, v2, v3;
    if (rowok){
      const float* Ap0 = A + (((size_t)sl * n + row) << 3);
      const float* Ap1 = A + (((size_t)(sl + 1) * n + row) << 3);
      v0 = *(const float4*)(Ap0);
      v1 = *(const float4*)(Ap0 + 4);
      v2 = *(const float4*)(Ap1);
      v3 = *(const float4*)(Ap1 + 4);
    } else {
      v0 = v1 = v2 = v3 = float4{0.f, 0.f, 0.f, 0.f};
    }
    __syncthreads();
    float vv[16] = {v0.x, v0.y, v0.z, v0.w, v1.x, v1.y, v1.z, v1.w,
                    v2.x, v2.y, v2.z, v2.w, v3.x, v3.y, v3.z, v3.w};
#pragma unroll
    for (int i = 0; i < 16; ++i) sa[lc + i][lr] = vv[i];
    __syncthreads();

    const float* Bp = B + (size_t)k0 * H + tc * 8;
#pragma unroll
    for (int k = 0; k < 32; ++k){
      float4 b0 = *(const float4*)(Bp + (size_t)k * H);
      float4 b1 = *(const float4*)(Bp + (size_t)k * H + 4);
      float4 a0 = *(const float4*)&sa[k][tr * 8];
      float4 a1 = *(const float4*)&sa[k][tr * 8 + 4];
      float aa[8] = {a0.x, a0.y, a0.z, a0.w, a1.x, a1.y, a1.z, a1.w};
      float bb[8] = {b0.x, b0.y, b0.z, b0.w, b1.x, b1.y, b1.z, b1.w};
#pragma unroll
      for (int i = 0; i < 8; ++i)
#pragma unroll
        for (int j = 0; j < 8; ++j) acc[i][j] += aa[i] * bb[j];
    }
  }
  float bb[8];
#pragma unroll
  for (int j = 0; j < 8; ++j) bb[j] = bias[tc * 8 + j];
#pragma unroll
  for (int i = 0; i < 8; ++i){
    int row = row0 + tr * 8 + i;
    if (row < n){
      float4 o0, o1;
      o0.x = fmaxf(acc[i][0] + bb[0], 0.f);
      o0.y = fmaxf(acc[i][1] + bb[1], 0.f);
      o0.z = fmaxf(acc[i][2] + bb[2], 0.f);
      o0.w = fmaxf(acc[i][3] + bb[3], 0.f);
      o1.x = fmaxf(acc[i][4] + bb[4], 0.f);
      o1.y = fmaxf(acc[i][5] + bb[5], 0.f);
      o1.z = fmaxf(acc[i][6] + bb[6], 0.f);
      o1.w = fmaxf(acc[i][7] + bb[7], 0.f);
      if (OUTMODE == 0){
        float di = disp[row];
        o0.x *= di; o0.y *= di; o0.z *= di; o0.w *= di;
        o1.x *= di; o1.y *= di; o1.z *= di; o1.w *= di;
        float* Cp = C + (((size_t)tc * n + row) << 3);
        *(float4*)(Cp) = o0;
        *(float4*)(Cp + 4) = o1;
      } else {
        float* Cp = C + (size_t)row * H + tc * 8;
        *(float4*)(Cp) = o0;
        *(float4*)(Cp + 4) = o1;
      }
    }
  }
}

// ---------------- graph offsets ----------------
__global__ void ghist_k(const int* __restrict__ batch, int* __restrict__ gc, int n){
  int i = blockIdx.x * 256 + threadIdx.x;
  if (i < n) atomicAdd(&gc[batch[i]], 1);
}

__global__ void gscan_k(const int* __restrict__ gc, int* __restrict__ go, int G){
  __shared__ int sd[1024];
  int t = threadIdx.x;
  int v = (t < G) ? gc[t] : 0;
  sd[t] = v;
  __syncthreads();
  for (int off = 1; off < 1024; off <<= 1){
    int add = (t >= off) ? sd[t - off] : 0;
    __syncthreads();
    sd[t] += add;
    __syncthreads();
  }
  if (t < G) go[t] = sd[t] - v;
}

// ---------------- fused decoder (h3 in PERM space, gather via inv) ----------------
__device__ __forceinline__ float sigf(float x){ return 1.f / (1.f + expf(-x)); }

__global__ __launch_bounds__(256) void decoder_k(
    const float* __restrict__ h3, const int* __restrict__ go, const int* __restrict__ gap,
    const int* __restrict__ inv,
    const float* __restrict__ Wih_f, const float* __restrict__ Whh_f,
    const float* __restrict__ bih_f, const float* __restrict__ bhh_f,
    const float* __restrict__ Wih_b, const float* __restrict__ Whh_b,
    const float* __restrict__ bih_b, const float* __restrict__ bhh_b,
    const float* __restrict__ Wred, const float* __restrict__ bred,
    const float* __restrict__ Wh1, const float* __restrict__ bh1,
    const float* __restrict__ Wh2, const float* __restrict__ bh2,
    float* __restrict__ out, int G){
  __shared__ float sx[4][H], shf[4][H], shb[4][H];
  int t = threadIdx.x;
  int g = t >> 6, l = t & 63;
  int gg = blockIdx.x * 4 + g;
  bool ok = gg < G;
  int idx = ok ? inv[go[gg] + gap[0]] : 0;
  float v0 = ok ? h3[(size_t)idx * H + l] : 0.f;
  float v1 = ok ? h3[(size_t)idx * H + 64 + l] : 0.f;
  sx[g][l] = v0; sx[g][64 + l] = v1;
  shf[g][l] = v0; shf[g][64 + l] = v1;
  shb[g][l] = v0; shb[g][64 + l] = v1;

  float bif[6], bhfv[6], bib[6], bhbv[6];
#pragma unroll
  for (int q = 0; q < 6; ++q){
    bif[q]  = bih_f[l + 64*q];  bhfv[q] = bhh_f[l + 64*q];
    bib[q]  = bih_b[l + 64*q];  bhbv[q] = bhh_b[l + 64*q];
  }
  float br0 = bred[l], br1 = bred[64 + l];
  float b10 = bh1[l],  b11 = bh1[64 + l];
  float w20 = Wh2[l*2], w21 = Wh2[l*2 + 1];
  float w22 = Wh2[(64+l)*2], w23 = Wh2[(64+l)*2 + 1];
  float b2o0 = bh2[0], b2o1 = bh2[1];
  __syncthreads();

  for (int step = 0; step < GAPLEN; ++step){
    float af[6] = {0,0,0,0,0,0}, ahf[6] = {0,0,0,0,0,0};
    float ab[6] = {0,0,0,0,0,0}, ahb[6] = {0,0,0,0,0,0};
    for (int k = 0; k < H; ++k){
      float xk = sx[g][k], hfk = shf[g][k], hbk = shb[g][k];
      const float* wif = Wih_f + (size_t)k * 384;
      const float* whf = Whh_f + (size_t)k * 384;
      const float* wib = Wih_b + (size_t)k * 384;
      const float* whb = Whh_b + (size_t)k * 384;
#pragma unroll
      for (int q = 0; q < 6; ++q){
        af[q]  += xk  * wif[l + 64*q];
        ahf[q] += hfk * whf[l + 64*q];
        ab[q]  += xk  * wib[l + 64*q];
        ahb[q] += hbk * whb[l + 64*q];
      }
    }
    float hf0 = shf[g][l], hf1 = shf[g][64 + l];
    float hb0 = shb[g][l], hb1 = shb[g][64 + l];
    float rf0 = sigf(af[0] + bif[0] + ahf[0] + bhfv[0]);
    float rf1 = sigf(af[1] + bif[1] + ahf[1] + bhfv[1]);
    float zf0 = sigf(af[2] + bif[2] + ahf[2] + bhfv[2]);
    float zf1 = sigf(af[3] + bif[3] + ahf[3] + bhfv[3]);
    float nf0 = tanhf(af[4] + bif[4] + rf0 * (ahf[4] + bhfv[4]));
    float nf1 = tanhf(af[5] + bif[5] + rf1 * (ahf[5] + bhfv[5]));
    float nhf0 = (1.f - zf0) * nf0 + zf0 * hf0;
    float nhf1 = (1.f - zf1) * nf1 + zf1 * hf1;
    float rb0 = sigf(ab[0] + bib[0] + ahb[0] + bhbv[0]);
    float rb1 = sigf(ab[1] + bib[1] + ahb[1] + bhbv[1]);
    float zb0 = sigf(ab[2] + bib[2] + ahb[2] + bhbv[2]);
    float zb1 = sigf(ab[3] + bib[3] + ahb[3] + bhbv[3]);
    float nb0 = tanhf(ab[4] + bib[4] + rb0 * (ahb[4] + bhbv[4]));
    float nb1 = tanhf(ab[5] + bib[5] + rb1 * (ahb[5] + bhbv[5]));
    float nhb0 = (1.f - zb0) * nb0 + zb0 * hb0;
    float nhb1 = (1.f - zb1) * nb1 + zb1 * hb1;
    __syncthreads();
    shf[g][l] = nhf0; shf[g][64 + l] = nhf1;
    shb[g][l] = nhb0; shb[g][64 + l] = nhb1;
    __syncthreads();

    float a10 = 0.f, a11 = 0.f, a20 = 0.f, a21 = 0.f;
    for (int k = 0; k < 2 * H; ++k){
      float ok_ = (k < H) ? shf[g][k] : shb[g][k - H];
      const float* w1 = Wh1 + (size_t)k * H;
      const float* w2 = Wred + (size_t)k * H;
      a10 += ok_ * w1[l];      a11 += ok_ * w1[64 + l];
      a20 += ok_ * w2[l];      a21 += ok_ * w2[64 + l];
    }
    float t10 = fmaxf(a10 + b10, 0.f);
    float t11 = fmaxf(a11 + b11, 0.f);
    float p0 = t10 * w20 + t11 * w22;
    float p1 = t10 * w21 + t11 * w23;
#pragma unroll
    for (int o = 32; o > 0; o >>= 1){
      p0 += __shfl_down(p0, o, 64);
      p1 += __shfl_down(p1, o, 64);
    }
    if (ok && l == 0){
      out[((size_t)gg * GAPLEN + step) * 2 + 0] = p0 + b2o0;
      out[((size_t)gg * GAPLEN + step) * 2 + 1] = p1 + b2o1;
    }
    __syncthreads();
    sx[g][l] = a20 + br0;
    sx[g][64 + l] = a21 + br1;
    __syncthreads();
  }
}

// =======================================================================
extern "C" void kernel_launch(void* const* d_in, const int* in_sizes, int n_in,
                              void* d_out, int out_size, void* d_ws, size_t ws_size,
                              hipStream_t stream) {
  const float* x     = (const float*)d_in[0];
  const int*   ei    = (const int*)d_in[1];
  const int*   batch = (const int*)d_in[2];
  const float* semb  = (const float*)d_in[3];
  const float* nemb  = (const float*)d_in[4];
  const float* W1 = (const float*)d_in[5];  const float* b1 = (const float*)d_in[6];
  const float* W2 = (const float*)d_in[7];  const float* b2 = (const float*)d_in[8];
  const float* W3 = (const float*)d_in[9];  const float* b3 = (const float*)d_in[10];
  const float* Wih_f = (const float*)d_in[11]; const float* Whh_f = (const float*)d_in[12];
  const float* bih_f = (const float*)d_in[13]; const float* bhh_f = (const float*)d_in[14];
  const float* Wih_b = (const float*)d_in[15]; const float* Whh_b = (const float*)d_in[16];
  const float* bih_b = (const float*)d_in[17]; const float* bhh_b = (const float*)d_in[18];
  const float* Wred = (const float*)d_in[19]; const float* bred = (const float*)d_in[20];
  const float* Wh1  = (const float*)d_in[21]; const float* bh1  = (const float*)d_in[22];
  const float* Wh2  = (const float*)d_in[23]; const float* bh2  = (const float*)d_in[24];
  const int* gap = (const int*)d_in[26];

  int N = in_sizes[0] / 12;
  int E = in_sizes[1] / 2;
  int G = out_size / (GAPLEN * 2);
  int NB = ceil_div(N, 128);
  float* out = (float*)d_out;

  char* ws = (char*)d_ws;
  size_t off = 0;
  auto alloc = [&](size_t bytes) -> void* {
    void* p = ws + off;
    off += (bytes + 511) & ~(size_t)511;
    return p;
  };
  float* feats  = (float*)alloc((size_t)N * 24 * 4);   // sliced [3][N][8], perm space
  float* agg1   = (float*)alloc((size_t)N * 24 * 4);   // sliced [3][N][8], perm space
  float* sl1    = (float*)alloc((size_t)N * H * 4);    // sliced A / final row-major h3 (perm)
  float* sl2    = (float*)alloc((size_t)N * H * 4);    // sliced B (perm)
  int*   cnt    = (int*)alloc((size_t)N * 4);
  float* dis    = (float*)alloc((size_t)N * 4);
  int*   rp     = (int*)alloc((size_t)N * 4);
  int*   csr    = (int*)alloc((size_t)E * 4);
  int*   ebuf   = (int*)alloc((size_t)E * 4);
  int4*  prc    = (int4*)alloc((size_t)N * 16);
  float* disp   = (float*)alloc((size_t)N * 4);
  int*   inv    = (int*)alloc((size_t)N * 4);
  int*   bh     = (int*)alloc((size_t)NB * 4);
  int*   bbase  = (int*)alloc((size_t)NB * 4);
  int*   bcur   = (int*)alloc((size_t)NB * 4);
  int*   dh     = (int*)alloc(256 * 4);
  int*   dbase  = (int*)alloc(256 * 4);
  int*   dcur   = (int*)alloc(256 * 4);
  int*   gc     = (int*)alloc((size_t)G * 4);
  int*   go     = (int*)alloc((size_t)G * 4);
  (void)ws_size; (void)n_in;

  hipMemsetAsync(bh, 0, (size_t)NB * 4, stream);
  hipMemsetAsync(bcur, 0, (size_t)NB * 4, stream);
  hipMemsetAsync(dh, 0, 256 * 4, stream);
  hipMemsetAsync(dcur, 0, 256 * 4, stream);
  hipMemsetAsync(gc, 0, (size_t)G * 4, stream);

  int nb256 = ceil_div(N, 256);
  int ebC   = ceil_div(E, CHUNK);

  // CSR build -> degree perm (prc/disp/inv) -> csr remap -> sliced perm feats
  bhistA_k<<<ebC, 256, 0, stream>>>(ei, bh, E, NB);
  bscan_k<<<1, 1024, 0, stream>>>(bh, bbase, NB);
  bpartC_k<<<ebC, 256, 0, stream>>>(ei, bbase, bcur, ebuf, E, NB);
  bbuildD_k<<<NB, 256, 0, stream>>>(ebuf, bh, bbase, rp, cnt, dis, csr, N);
  dhist_k<<<nb256, 256, 0, stream>>>(cnt, dh, N);
  dscan_k<<<1, 256, 0, stream>>>(dh, dbase);
  dperm_k<<<nb256, 256, 0, stream>>>(cnt, rp, dis, dbase, dcur, prc, disp, inv, N);
  remap_k<<<ceil_div(E, 256), 256, 0, stream>>>(csr, inv, E);
  build_feats_k<<<nb256, 256, 0, stream>>>(x, semb, nemb, prc, feats, N);

  int TB = ceil_div(N, 128);
  int gemmb = ceil_div(N, 64);

  // layer 1: sliced agg (3 slices) -> gemm18 (sliced+scaled out)
  aggp_k<1><<<4 * TB, 256, 0, stream>>>(feats, prc, csr, agg1, N, 0);
  gemm18_k<<<ceil_div(N, 8), 256, 0, stream>>>(agg1, W1, b1, disp, sl1, N);
  // layer 2: two phase launches (slices 0-7, 8-15) -> gemm
  aggp_k<0><<<8 * TB, 256, 0, stream>>>(sl1, prc, csr, sl2, N, 0);
  aggp_k<0><<<8 * TB, 256, 0, stream>>>(sl1, prc, csr, sl2, N, 8);
  gemm128_k<0><<<gemmb, 128, 0, stream>>>(sl2, W2, b2, disp, sl1, N);
  // layer 3
  aggp_k<0><<<8 * TB, 256, 0, stream>>>(sl1, prc, csr, sl2, N, 0);
  aggp_k<0><<<8 * TB, 256, 0, stream>>>(sl1, prc, csr, sl2, N, 8);
  gemm128_k<1><<<gemmb, 128, 0, stream>>>(sl2, W3, b3, disp, sl1, N);  // sl1 = row-major h3 (perm)

  // graph offsets + fused decoder
  ghist_k<<<nb256, 256, 0, stream>>>(batch, gc, N);
  gscan_k<<<1, 1024, 0, stream>>>(gc, go, G);
  decoder_k<<<ceil_div(G, 4), 256, 0, stream>>>(sl1, go, gap, inv,
                                                Wih_f, Whh_f, bih_f, bhh_f,
                                                Wih_b, Whh_b, bih_b, bhh_b,
                                                Wred, bred, Wh1, bh1, Wh2, bh2,
                                                out, G);
}